// Round 6
// baseline (321.406 us; speedup 1.0000x reference)
//
#include <hip/hip_runtime.h>
#include <cstdint>
#include <math.h>

#define T_SEQ 2048
#define BATCH 2
#define NH 16
#define NKV 4
#define HD 128

typedef __attribute__((ext_vector_type(8))) short short8;
typedef __attribute__((ext_vector_type(4))) float f32x4;

__device__ __forceinline__ ushort f2bf(float f) {
  uint32_t u = __builtin_bit_cast(uint32_t, f);
  u += 0x7FFF + ((u >> 16) & 1);  // RNE
  return (ushort)(u >> 16);
}
__device__ __forceinline__ ushort f2bf_trunc(float f) {
  return (ushort)(__builtin_bit_cast(uint32_t, f) >> 16);
}
__device__ __forceinline__ float bf2f(ushort u) {
  uint32_t v = ((uint32_t)u) << 16;
  return __builtin_bit_cast(float, v);
}
// async 16B/lane global->LDS DMA. lds must be wave-uniform; hw adds lane*16.
__device__ __forceinline__ void ld16(void* lds, const void* g) {
  __builtin_amdgcn_global_load_lds((const __attribute__((address_space(1))) void*)g,
                                   (__attribute__((address_space(3))) void*)lds,
                                   16, 0, 0);
}

// ---------------------------------------------------------------------------
// Fused prep: x f32->bf16 convert + 4 weight transposes (f32 [K][N] -> bf16
// [N][K]). Regions by blockIdx.x: [0,8192) x-convert; then Wq 4096, Wk 1024,
// Wv 1024, Wo 4096 transpose blocks (32x32 tiles).
// ---------------------------------------------------------------------------
__global__ __launch_bounds__(256) void prep(
    const float* __restrict__ x, ushort* __restrict__ xb,
    const float* __restrict__ Wq, const float* __restrict__ Wk,
    const float* __restrict__ Wv, const float* __restrict__ Wo,
    ushort* __restrict__ wqkvT, ushort* __restrict__ woT) {
  __shared__ float tile[32][33];
  const int bid = blockIdx.x;
  const int tid = threadIdx.x;
  if (bid < 8192) {  // x convert: 4096*2048 elems, 4/thread
    int i = (bid * 256 + tid) * 4;
    float4 v = *(const float4*)&x[i];
    ushort4 o;
    o.x = f2bf(v.x); o.y = f2bf(v.y); o.z = f2bf(v.z); o.w = f2bf(v.w);
    *(ushort4*)&xb[i] = o;
    return;
  }
  const float* in;
  ushort* out;
  int N, lid;
  if (bid < 12288)      { in = Wq; out = wqkvT;                        N = 2048; lid = bid - 8192; }
  else if (bid < 13312) { in = Wk; out = wqkvT + (size_t)2048 * 2048;  N = 512;  lid = bid - 12288; }
  else if (bid < 14336) { in = Wv; out = wqkvT + (size_t)2560 * 2048;  N = 512;  lid = bid - 13312; }
  else                  { in = Wo; out = woT;                          N = 2048; lid = bid - 14336; }
  const int K = 2048;
  const int nb = N / 32;
  const int n0 = (lid % nb) * 32, k0 = (lid / nb) * 32;
  const int r = tid >> 3, c4 = (tid & 7) << 2;
  float4 v = *(const float4*)&in[(size_t)(k0 + r) * N + n0 + c4];
  tile[r][c4 + 0] = v.x; tile[r][c4 + 1] = v.y;
  tile[r][c4 + 2] = v.z; tile[r][c4 + 3] = v.w;
  __syncthreads();
  ushort4 o;
  o.x = f2bf(tile[c4 + 0][r]); o.y = f2bf(tile[c4 + 1][r]);
  o.z = f2bf(tile[c4 + 2][r]); o.w = f2bf(tile[c4 + 3][r]);
  *(ushort4*)&out[(size_t)(n0 + r) * K + k0 + c4] = o;
}

// ---------------------------------------------------------------------------
// bf16 GEMM C[M,N] = A[M,K] * Bt[N,K]^T. 128x128 tile, BK=32, 4 waves (2x2),
// global_load_lds staging, XOR-swizzled LDS. SIMPLE epilogue only. Used for
// gemm2 (N=2048 -> 512 blocks = 2/CU balanced coverage).
// ---------------------------------------------------------------------------
template <typename OutT>
__global__ __launch_bounds__(256) void gemm_bt(const ushort* __restrict__ A,
                                               const ushort* __restrict__ Bt,
                                               OutT* __restrict__ C,
                                               int M, int N, int K) {
  __shared__ __align__(16) ushort As[128 * 32];
  __shared__ __align__(16) ushort Bs[128 * 32];
  const int tid = threadIdx.x;
  const int w = tid >> 6, l = tid & 63;
  const int wr = w >> 1, wc = w & 1;
  const int quad = l >> 4, l15 = l & 15;
  const int bm = blockIdx.y * 128, bn = blockIdx.x * 128;

  f32x4 acc[4][4];
#pragma unroll
  for (int mi = 0; mi < 4; ++mi)
#pragma unroll
    for (int ni = 0; ni < 4; ++ni)
#pragma unroll
      for (int r = 0; r < 4; ++r) acc[mi][ni][r] = 0.f;

  for (int k0 = 0; k0 < K; k0 += 32) {
    __syncthreads();
#pragma unroll
    for (int j = 0; j < 2; ++j) {
      int r0 = w * 32 + j * 16;
      int row = r0 + (l >> 2);
      int gc = (l & 3) ^ ((row >> 1) & 3);
      ld16(&As[r0 * 32], &A[(size_t)(bm + row) * K + k0 + gc * 8]);
      ld16(&Bs[r0 * 32], &Bt[(size_t)(bn + row) * K + k0 + gc * 8]);
    }
    __syncthreads();
    short8 af[4], bf[4];
#pragma unroll
    for (int mi = 0; mi < 4; ++mi) {
      int m = wr * 64 + mi * 16 + l15;
      af[mi] = *(const short8*)&As[m * 32 + (quad ^ ((m >> 1) & 3)) * 8];
    }
#pragma unroll
    for (int ni = 0; ni < 4; ++ni) {
      int n = wc * 64 + ni * 16 + l15;
      bf[ni] = *(const short8*)&Bs[n * 32 + (quad ^ ((n >> 1) & 3)) * 8];
    }
#pragma unroll
    for (int mi = 0; mi < 4; ++mi)
#pragma unroll
      for (int ni = 0; ni < 4; ++ni)
        acc[mi][ni] = __builtin_amdgcn_mfma_f32_16x16x32_bf16(af[mi], bf[ni], acc[mi][ni], 0, 0, 0);
  }
  // epilogue: C/D layout col=lane&15, row=quad*4+reg
#pragma unroll
  for (int mi = 0; mi < 4; ++mi)
#pragma unroll
    for (int ni = 0; ni < 4; ++ni)
#pragma unroll
      for (int r = 0; r < 4; ++r) {
        int grow = bm + wr * 64 + mi * 16 + quad * 4 + r;
        int gcol = bn + wc * 64 + ni * 16 + l15;
        if constexpr (__is_same(OutT, ushort))
          C[(size_t)grow * N + gcol] = f2bf(acc[mi][ni][r]);
        else
          C[(size_t)grow * N + gcol] = acc[mi][ni][r];
      }
}

// ---------------------------------------------------------------------------
// 256x256 8-wave BK=64 GEMM, m201-faithful 4-phase schedule. Round-5 rebuild:
// the v1 attempt had (a) prefetch slack of only 1 phase (HBM ~900cy >> 350cy
// -> exposed stall every tile) and (b) ds_reads issued AFTER the phase
// barrier (latency exposed instead of hidden under barrier-wait). 6150
// cyc/tile vs m201's ~3300.
// Fixed pipeline (tile T, phases P0-P3; halves A0/A1/B0/B1 = stage units
// 0/1/2/3; tile T lives in buf[T&1]):
//   stage at:  P0 -> (T+1).B0   P1 -> (T+1).B1   P2 -> (T+2).A0   P3 -> (T+2).A1
//   slack: every half staged >=3 phases before its tile's P0. vmcnt(6) ONCE
//   per tile at P0 (FIFO retire = exactly tile T's 8 loads); tail vmcnt(0).
//   MFMA order: P0 alo*blo, P1 ahi*blo, P2 ahi*bhi, P3 alo*bhi
//   -> A-slot last read P1, B-slot last read P2: every staged DMA lands in a
//   slot freed by a barrier at least one phase earlier (no latency-gap races).
//   ds_reads for P1/P2 issue PRE-barrier (hide under barrier wait); P0's
//   post-barrier (new buffer, unavoidable once per tile).
// Frag regs: alo/ahi 32 VGPR each, blo/bhi 16 each, acc 128 -> peak ~210.
// XCD swizzle: 192 blocks % 8 == 0 -> bijective chunked remap.
// ---------------------------------------------------------------------------
template <typename OutT>
__global__ __launch_bounds__(512, 2) void gemm_bt256(const ushort* __restrict__ A,
                                                     const ushort* __restrict__ Bt,
                                                     OutT* __restrict__ C,
                                                     int M, int N, int K) {
  __shared__ __align__(16) ushort As[2][256 * 64];
  __shared__ __align__(16) ushort Bs[2][256 * 64];
  const int tid = threadIdx.x;
  const int w = tid >> 6, l = tid & 63;
  const int wr = w >> 2, wc = w & 3;
  const int quad = l >> 4, l15 = l & 15;

  // XCD-aware bijective swizzle (nwg = 192, %8==0)
  const int nwg = gridDim.x * gridDim.y;
  int lin = blockIdx.y * gridDim.x + blockIdx.x;
  const int cpx = nwg >> 3;
  lin = (lin & 7) * cpx + (lin >> 3);
  const int bm = (lin / gridDim.x) * 256, bn = (lin % gridDim.x) * 256;

  f32x4 acc[8][4];
#pragma unroll
  for (int mi = 0; mi < 8; ++mi)
#pragma unroll
    for (int ni = 0; ni < 4; ++ni)
#pragma unroll
      for (int r = 0; r < 4; ++r) acc[mi][ni][r] = 0.f;

  // stage unit u of the K-tile at k0 into buf: u0=A rows 0-127, u1=A 128-255,
  // u2=B 0-127, u3=B 128-255. 2 ld16/thread (16KB half-tile), source
  // pre-swizzled so linear LDS + XOR read = conflict-free (verified: 0).
  auto stage_unit = [&](int k0, int buf, int u) {
    const ushort* __restrict__ src = (u < 2) ? A : Bt;
    ushort* dst = (u < 2) ? &As[buf][0] : &Bs[buf][0];
    const int goff = (u < 2) ? bm : bn;
    const int rb = (u & 1) * 128;
#pragma unroll
    for (int j = 0; j < 2; ++j) {
      int r0 = rb + j * 64 + w * 8;  // wave-uniform LDS row base
      int row = r0 + (l >> 3);
      int gc = (l & 7) ^ (row & 7);
      ld16(&dst[r0 * 64], &src[(size_t)(goff + row) * K + k0 + gc * 8]);
    }
  };

  short8 alo[4][2], ahi[4][2], blo[2][2], bhi[2][2];

#define LOAD_A(dst, mh)                                                          \
  _Pragma("unroll") for (int i = 0; i < 4; ++i) {                                \
    int m = wr * 128 + ((mh) * 4 + i) * 16 + l15;                                \
    _Pragma("unroll") for (int ks = 0; ks < 2; ++ks)                             \
      dst[i][ks] = *(const short8*)&as[m * 64 + ((ks * 4 + quad) ^ (m & 7)) * 8]; \
  }
#define LOAD_B(dst, nh)                                                          \
  _Pragma("unroll") for (int jn = 0; jn < 2; ++jn) {                             \
    int n = wc * 64 + ((nh) * 2 + jn) * 16 + l15;                                \
    _Pragma("unroll") for (int ks = 0; ks < 2; ++ks)                             \
      dst[jn][ks] = *(const short8*)&bs[n * 64 + ((ks * 4 + quad) ^ (n & 7)) * 8]; \
  }
#define MFMA_Q(afr, mh, bfr, nh)                                                 \
  __builtin_amdgcn_s_setprio(1);                                                 \
  _Pragma("unroll") for (int ks = 0; ks < 2; ++ks)                               \
  _Pragma("unroll") for (int i = 0; i < 4; ++i)                                  \
  _Pragma("unroll") for (int jn = 0; jn < 2; ++jn)                               \
    acc[(mh) * 4 + i][(nh) * 2 + jn] = __builtin_amdgcn_mfma_f32_16x16x32_bf16(  \
        afr[i][ks], bfr[jn][ks], acc[(mh) * 4 + i][(nh) * 2 + jn], 0, 0, 0);     \
  __builtin_amdgcn_s_setprio(0);

  const int NT = K >> 6;  // 32
  // prologue: T0 fully + T1.A0, T1.A1 (12 loads in flight)
  stage_unit(0, 0, 0); stage_unit(0, 0, 1);
  stage_unit(0, 0, 2); stage_unit(0, 0, 3);
  stage_unit(64, 1, 0); stage_unit(64, 1, 1);

  for (int kt = 0; kt < NT; ++kt) {
    const int buf = kt & 1;
    const ushort* as = &As[buf][0];
    const ushort* bs = &Bs[buf][0];
    const int n1 = (kt + 1) << 6, n2 = (kt + 2) << 6;

    // ---- P0: stage (T+1).B0; vmcnt(6) retires exactly tile-T's 8 loads.
    if (kt + 1 < NT) {
      stage_unit(n1, buf ^ 1, 2);
      asm volatile("s_waitcnt vmcnt(6)" ::: "memory");
    } else {
      asm volatile("s_waitcnt vmcnt(0)" ::: "memory");
    }
    asm volatile("s_barrier" ::: "memory");
    LOAD_A(alo, 0);
    LOAD_B(blo, 0);
    MFMA_Q(alo, 0, blo, 0);
    asm volatile("s_barrier" ::: "memory");

    // ---- P1: stage (T+1).B1; pre-barrier ds_read ahi (hides under barrier)
    if (kt + 1 < NT) stage_unit(n1, buf ^ 1, 3);
    LOAD_A(ahi, 1);
    asm volatile("s_barrier" ::: "memory");
    MFMA_Q(ahi, 1, blo, 0);
    asm volatile("s_barrier" ::: "memory");
    // A-slot of tile T fully read (alo@P0, ahi@P1) -> freed for (T+2).A

    // ---- P2: stage (T+2).A0 (slot freed at P1-end barrier); pre-read bhi
    if (kt + 2 < NT) stage_unit(n2, buf, 0);
    LOAD_B(bhi, 1);
    asm volatile("s_barrier" ::: "memory");
    MFMA_Q(ahi, 1, bhi, 1);
    asm volatile("s_barrier" ::: "memory");
    // B-slot of tile T fully read (blo@P0, bhi@P2) -> freed for (T+2).B

    // ---- P3: stage (T+2).A1; all frags live in regs, 0 ds_reads
    if (kt + 2 < NT) stage_unit(n2, buf, 1);
    MFMA_Q(alo, 0, bhi, 1);
    // no barrier: P3 is register-only; next P0's barrier re-syncs.
  }
#undef LOAD_A
#undef LOAD_B
#undef MFMA_Q

  // epilogue: C/D layout col=lane&15, row=quad*4+reg
#pragma unroll
  for (int mi = 0; mi < 8; ++mi)
#pragma unroll
    for (int ni = 0; ni < 4; ++ni)
#pragma unroll
      for (int r = 0; r < 4; ++r) {
        int grow = bm + wr * 128 + mi * 16 + quad * 4 + r;
        int gcol = bn + wc * 64 + ni * 16 + l15;
        if constexpr (__is_same(OutT, ushort))
          C[(size_t)grow * N + gcol] = f2bf(acc[mi][ni][r]);
        else
          C[(size_t)grow * N + gcol] = acc[mi][ni][r];
      }
}

// ---------------------------------------------------------------------------
// RoPE in-place on bf16 K columns of qkv [4096][3072] (cols 2048..2559).
// Q rope is fused into attn.
// ---------------------------------------------------------------------------
__global__ __launch_bounds__(256) void rope_k_bf16(ushort* __restrict__ qkv) {
  int idx = blockIdx.x * 256 + threadIdx.x;
  const int PAIRS_PER_ROW = 256;  // NKV*64
  if (idx >= BATCH * T_SEQ * PAIRS_PER_ROW) return;
  int row = idx >> 8;
  int kp = idx & 255;
  int t = row & (T_SEQ - 1);
  int i = kp & 63;
  ushort* ptr = qkv + (size_t)row * 3072 + 2048 + 2 * kp;
  float inv = expf((float)i * -0.14391156831212788f);  // ln(10000)/64
  float ang = (float)t * inv;
  float sn, cs;
  sincosf(ang, &sn, &cs);
  float x1 = bf2f(ptr[0]), x2 = bf2f(ptr[1]);
  ptr[0] = f2bf(x1 * cs - x2 * sn);
  ptr[1] = f2bf(x1 * sn + x2 * cs);
}

// ---------------------------------------------------------------------------
// v columns of qkv [4096][3072] (cols 2560..3071) -> vT [512][4096] bf16.
// grid (4096/32, 512/32).
// ---------------------------------------------------------------------------
__global__ __launch_bounds__(256) void transpose_v(const ushort* __restrict__ qkv,
                                                   ushort* __restrict__ vT) {
  __shared__ ushort tile[32][34];
  int m0 = blockIdx.x * 32, d0 = blockIdx.y * 32;
  int r = threadIdx.x >> 3, c4 = (threadIdx.x & 7) << 2;
  ushort4 v = *(const ushort4*)&qkv[(size_t)(m0 + r) * 3072 + 2560 + d0 + c4];
  tile[r][c4 + 0] = v.x; tile[r][c4 + 1] = v.y;
  tile[r][c4 + 2] = v.z; tile[r][c4 + 3] = v.w;
  __syncthreads();
  ushort4 o;
  o.x = tile[c4 + 0][r]; o.y = tile[c4 + 1][r];
  o.z = tile[c4 + 2][r]; o.w = tile[c4 + 3][r];
  *(ushort4*)&vT[(size_t)(d0 + r) * 4096 + m0 + c4] = o;
}

// ---------------------------------------------------------------------------
// MFMA flash attention v5 (round-0 exact — 77us measured; v6-v9 occupancy
// experiments all regressed; keep).
// grid (32, NKV, B), 512 thr = 8 waves. Block covers 4 q-heads x 32 q-rows
// sharing K/V staging; two complementary q-tiles (63-bx, bx) -> exactly 33
// k-iters/block, 256-block balanced grid. No-max softmax, double-buffered
// K/V, SC folded into Q frags, truncated P converts. LDS 80KB.
// ---------------------------------------------------------------------------
__global__ __launch_bounds__(512, 2) void attn_mfma(const ushort* __restrict__ qkv,
                                                    const ushort* __restrict__ vT,
                                                    ushort* __restrict__ ao) {
  __shared__ __align__(16) ushort Ks[2][64 * 128];
  __shared__ __align__(16) ushort Vt[2][128 * 64];
  __shared__ __align__(16) ushort Ps[8][16 * 64];
  const int tid = threadIdx.x;
  const int w = tid >> 6, l = tid & 63;
  const int quad = l >> 4, l15 = l & 15;
  const int hw = w >> 1, sub = w & 1;
  const int kvh = blockIdx.y, b = blockIdx.z;
  const int h = kvh * 4 + hw;
  const size_t krow0 = (size_t)b * T_SEQ;
  const float SC = 0.12751744595764253f;  // (1/sqrt(128)) * log2(e)

  ushort* pw = Ps[w];
  const int within = l & 7;
  const int colbase = l15 >> 3;  // 0 or 1

  auto stage = [&](int kt, int bufi) {
    const int kt0 = kt << 6;
    ushort* kb = Ks[bufi];
    ushort* vb = Vt[bufi];
#pragma unroll
    for (int j = 0; j < 2; ++j) {  // K tile 64x128
      int r0 = w * 8 + j * 4;
      int row = r0 + (l >> 4);
      int gc = (l & 15) ^ ((row >> 1) & 7);
      ld16(&kb[r0 * 128], &qkv[(krow0 + kt0 + row) * 3072 + 2048 + kvh * 128 + gc * 8]);
    }
#pragma unroll
    for (int j = 0; j < 2; ++j) {  // V^T tile 128x64
      int r0 = w * 16 + j * 8;
      int row = r0 + (l >> 3);
      int gc = (l & 7) ^ (row & 7);
      ld16(&vb[r0 * 64], &vT[(size_t)(kvh * 128 + row) * 4096 + krow0 + kt0 + gc * 8]);
    }
  };

#pragma unroll 1
  for (int ph = 0; ph < 2; ++ph) {
    const int qt = ph ? (int)blockIdx.x : 63 - (int)blockIdx.x;
    const int qt0 = qt << 5;
    const size_t qrow0 = krow0 + qt0;

    // Q fragments in registers; RoPE + SC folded in.
    const int t_pos = qt0 + sub * 16 + l15;
    short8 qf[4];
#pragma unroll
    for (int kc = 0; kc < 4; ++kc) {
      short8 raw = *(const short8*)&qkv[(qrow0 + sub * 16 + l15) * 3072 + h * 128 + kc * 32 + quad * 8];
#pragma unroll
      for (int u = 0; u < 4; ++u) {
        int i_idx = kc * 16 + quad * 4 + u;
        float inv = expf((float)i_idx * -0.14391156831212788f);  // ln(10000)/64
        float sn, cs;
        sincosf((float)t_pos * inv, &sn, &cs);
        cs *= SC; sn *= SC;
        float x1 = bf2f((ushort)raw[2 * u]);
        float x2 = bf2f((ushort)raw[2 * u + 1]);
        qf[kc][2 * u]     = (short)f2bf(x1 * cs - x2 * sn);
        qf[kc][2 * u + 1] = (short)f2bf(x1 * sn + x2 * cs);
      }
    }

    f32x4 oacc[8];
#pragma unroll
    for (int i = 0; i < 8; ++i)
#pragma unroll
      for (int r = 0; r < 4; ++r) oacc[i][r] = 0.f;
    float lpart[4] = {0.f, 0.f, 0.f, 0.f};

    const int nkt = (qt >> 1) + 1;
    __syncthreads();  // prior phase's LDS reads complete before re-priming
    stage(0, 0);
    for (int kt = 0; kt < nkt; ++kt) {
      __syncthreads();  // (vmcnt drain) stage(kt) landed; prior buffer free
      if (kt + 1 < nkt) stage(kt + 1, (kt + 1) & 1);
      const ushort* kb = Ks[kt & 1];
      const ushort* vb = Vt[kt & 1];

      // S = Q K^T (wave rows sub*16.., cols 0..63); already scaled by SC
      f32x4 sacc[4];
#pragma unroll
      for (int ni = 0; ni < 4; ++ni)
#pragma unroll
        for (int r = 0; r < 4; ++r) sacc[ni][r] = 0.f;
#pragma unroll
      for (int kc = 0; kc < 4; ++kc) {
#pragma unroll
        for (int ni = 0; ni < 4; ++ni) {
          int n = ni * 16 + l15;
          short8 bfr = *(const short8*)&kb[n * 128 + ((kc * 4 + quad) ^ ((n >> 1) & 7)) * 8];
          sacc[ni] = __builtin_amdgcn_mfma_f32_16x16x32_bf16(qf[kc], bfr, sacc[ni], 0, 0, 0);
        }
      }

      // p = exp2(s); stream to LDS (truncated bf16); accumulate partial l.
      const int kt0 = kt << 6;
      if (kt == nkt - 1) {  // diagonal tile: causal mask
        const int rowg = qt0 + sub * 16 + quad * 4;
#pragma unroll
        for (int ni = 0; ni < 4; ++ni) {
          const int colid = kt0 + ni * 16 + l15;
#pragma unroll
          for (int r = 0; r < 4; ++r) {
            float s = (colid > rowg + r) ? -1e30f : sacc[ni][r];
            float pv = __builtin_amdgcn_exp2f(s);
            lpart[r] += pv;
            int prow = quad * 4 + r;
            pw[prow * 64 + (((ni * 2 + colbase) ^ (prow & 7)) << 3) + within] = f2bf_trunc(pv);
          }
        }
      } else {
#pragma unroll
        for (int ni = 0; ni < 4; ++ni)
#pragma unroll
          for (int r = 0; r < 4; ++r) {
            float pv = __builtin_amdgcn_exp2f(sacc[ni][r]);
            lpart[r] += pv;
            int prow = quad * 4 + r;
            pw[prow * 64 + (((ni * 2 + colbase) ^ (prow & 7)) << 3) + within] = f2bf_trunc(pv);
          }
      }

      // O += P V  (A = Ps rows m=l&15, B = Vt rows d)
#pragma unroll
      for (int kc = 0; kc < 2; ++kc) {
        short8 a = *(const short8*)&pw[l15 * 64 + ((kc * 4 + quad) ^ (l15 & 7)) * 8];
#pragma unroll
        for (int ni2 = 0; ni2 < 8; ++ni2) {
          int d = ni2 * 16 + l15;
          short8 bfr = *(const short8*)&vb[d * 64 + ((kc * 4 + quad) ^ (d & 7)) * 8];
          oacc[ni2] = __builtin_amdgcn_mfma_f32_16x16x32_bf16(a, bfr, oacc[ni2], 0, 0, 0);
        }
      }
    }

    // phase epilogue: one butterfly reduce of l per row, normalize + store
#pragma unroll
    for (int r = 0; r < 4; ++r) {
      float lv = lpart[r];
      lv += __shfl_xor(lv, 1);
      lv += __shfl_xor(lv, 2);
      lv += __shfl_xor(lv, 4);
      lv += __shfl_xor(lv, 8);
      float inv = 1.f / lv;
      size_t grow = qrow0 + sub * 16 + quad * 4 + r;
#pragma unroll
      for (int ni2 = 0; ni2 < 8; ++ni2)
        ao[grow * 2048 + h * 128 + ni2 * 16 + l15] = f2bf(oacc[ni2][r] * inv);
    }
  }
}

// ---------------------------------------------------------------------------
extern "C" void kernel_launch(void* const* d_in, const int* in_sizes, int n_in,
                              void* d_out, int out_size, void* d_ws, size_t ws_size,
                              hipStream_t stream) {
  const float* x  = (const float*)d_in[0];
  const float* Wq = (const float*)d_in[1];
  const float* Wk = (const float*)d_in[2];
  const float* Wv = (const float*)d_in[3];
  const float* Wo = (const float*)d_in[4];
  float* y = (float*)d_out;

  const int M = BATCH * T_SEQ;  // 4096
  ushort* xb    = (ushort*)d_ws;                    // 4096*2048  (16 MB)
  ushort* wqkvT = xb + (size_t)M * 2048;            // 3072*2048  (12 MB)
  ushort* woT   = wqkvT + (size_t)3072 * 2048;      // 2048*2048  ( 8 MB)
  ushort* qkv   = woT + (size_t)2048 * 2048;        // 4096*3072  (24 MB)
  ushort* vTb   = qkv + (size_t)M * 3072;           // 512*4096   ( 4 MB)
  ushort* aob   = vTb + (size_t)512 * 4096;         // 4096*2048  (16 MB)

  prep<<<18432, 256, 0, stream>>>(x, xb, Wq, Wk, Wv, Wo, wqkvT, woT);

  gemm_bt256<ushort><<<dim3(3072 / 256, M / 256), 512, 0, stream>>>(
      xb, wqkvT, qkv, M, 3072, 2048);

  rope_k_bf16<<<(M * 256 + 255) / 256, 256, 0, stream>>>(qkv);
  transpose_v<<<dim3(M / 32, 512 / 32), 256, 0, stream>>>(qkv, vTb);

  attn_mfma<<<dim3(32, NKV, BATCH), 512, 0, stream>>>(qkv, vTb, aob);

  gemm_bt<float><<<dim3(2048 / 128, M / 128), 256, 0, stream>>>(
      aob, woT, y, M, 2048, 2048);
}

// Round 7
// 308.364 us; speedup vs baseline: 1.0423x; 1.0423x over previous
//
#include <hip/hip_runtime.h>
#include <cstdint>
#include <math.h>

#define T_SEQ 2048
#define BATCH 2
#define NH 16
#define NKV 4
#define HD 128

typedef __attribute__((ext_vector_type(8))) short short8;
typedef __attribute__((ext_vector_type(4))) float f32x4;

__device__ __forceinline__ ushort f2bf(float f) {
  uint32_t u = __builtin_bit_cast(uint32_t, f);
  u += 0x7FFF + ((u >> 16) & 1);  // RNE
  return (ushort)(u >> 16);
}
__device__ __forceinline__ ushort f2bf_trunc(float f) {
  return (ushort)(__builtin_bit_cast(uint32_t, f) >> 16);
}
__device__ __forceinline__ float bf2f(ushort u) {
  uint32_t v = ((uint32_t)u) << 16;
  return __builtin_bit_cast(float, v);
}
// async 16B/lane global->LDS DMA. lds must be wave-uniform; hw adds lane*16.
__device__ __forceinline__ void ld16(void* lds, const void* g) {
  __builtin_amdgcn_global_load_lds((const __attribute__((address_space(1))) void*)g,
                                   (__attribute__((address_space(3))) void*)lds,
                                   16, 0, 0);
}

// ---------------------------------------------------------------------------
// Fused prep: x f32->bf16 convert + 4 weight transposes (f32 [K][N] -> bf16
// [N][K]). Regions by blockIdx.x: [0,8192) x-convert; then Wq 4096, Wk 1024,
// Wv 1024, Wo 4096 transpose blocks (32x32 tiles).
// ---------------------------------------------------------------------------
__global__ __launch_bounds__(256) void prep(
    const float* __restrict__ x, ushort* __restrict__ xb,
    const float* __restrict__ Wq, const float* __restrict__ Wk,
    const float* __restrict__ Wv, const float* __restrict__ Wo,
    ushort* __restrict__ wqkvT, ushort* __restrict__ woT) {
  __shared__ float tile[32][33];
  const int bid = blockIdx.x;
  const int tid = threadIdx.x;
  if (bid < 8192) {  // x convert: 4096*2048 elems, 4/thread
    int i = (bid * 256 + tid) * 4;
    float4 v = *(const float4*)&x[i];
    ushort4 o;
    o.x = f2bf(v.x); o.y = f2bf(v.y); o.z = f2bf(v.z); o.w = f2bf(v.w);
    *(ushort4*)&xb[i] = o;
    return;
  }
  const float* in;
  ushort* out;
  int N, lid;
  if (bid < 12288)      { in = Wq; out = wqkvT;                        N = 2048; lid = bid - 8192; }
  else if (bid < 13312) { in = Wk; out = wqkvT + (size_t)2048 * 2048;  N = 512;  lid = bid - 12288; }
  else if (bid < 14336) { in = Wv; out = wqkvT + (size_t)2560 * 2048;  N = 512;  lid = bid - 13312; }
  else                  { in = Wo; out = woT;                          N = 2048; lid = bid - 14336; }
  const int K = 2048;
  const int nb = N / 32;
  const int n0 = (lid % nb) * 32, k0 = (lid / nb) * 32;
  const int r = tid >> 3, c4 = (tid & 7) << 2;
  float4 v = *(const float4*)&in[(size_t)(k0 + r) * N + n0 + c4];
  tile[r][c4 + 0] = v.x; tile[r][c4 + 1] = v.y;
  tile[r][c4 + 2] = v.z; tile[r][c4 + 3] = v.w;
  __syncthreads();
  ushort4 o;
  o.x = f2bf(tile[c4 + 0][r]); o.y = f2bf(tile[c4 + 1][r]);
  o.z = f2bf(tile[c4 + 2][r]); o.w = f2bf(tile[c4 + 3][r]);
  *(ushort4*)&out[(size_t)(n0 + r) * K + k0 + c4] = o;
}

// ---------------------------------------------------------------------------
// bf16 GEMM C[M,N] = A[M,K] * Bt[N,K]^T. 128x128 tile, BK=32, 4 waves (2x2),
// global_load_lds staging, XOR-swizzled LDS. SIMPLE epilogue only (fused
// complex epilogues spill — keep it to stores). Used for gemm2.
// Round 5-6 lesson: two 256x256 4-phase rebuilds both landed ~81us (vs ~70
// here) with MfmaUtil stuck at 25% — the 8-phase template needs choreography
// we can't verify without asm; this 128x128 m97 structure stays.
// ---------------------------------------------------------------------------
template <typename OutT>
__global__ __launch_bounds__(256) void gemm_bt(const ushort* __restrict__ A,
                                               const ushort* __restrict__ Bt,
                                               OutT* __restrict__ C,
                                               int M, int N, int K) {
  __shared__ __align__(16) ushort As[128 * 32];
  __shared__ __align__(16) ushort Bs[128 * 32];
  const int tid = threadIdx.x;
  const int w = tid >> 6, l = tid & 63;
  const int wr = w >> 1, wc = w & 1;
  const int quad = l >> 4, l15 = l & 15;
  const int bm = blockIdx.y * 128, bn = blockIdx.x * 128;

  f32x4 acc[4][4];
#pragma unroll
  for (int mi = 0; mi < 4; ++mi)
#pragma unroll
    for (int ni = 0; ni < 4; ++ni)
#pragma unroll
      for (int r = 0; r < 4; ++r) acc[mi][ni][r] = 0.f;

  for (int k0 = 0; k0 < K; k0 += 32) {
    __syncthreads();
#pragma unroll
    for (int j = 0; j < 2; ++j) {
      int r0 = w * 32 + j * 16;
      int row = r0 + (l >> 2);
      int gc = (l & 3) ^ ((row >> 1) & 3);
      ld16(&As[r0 * 32], &A[(size_t)(bm + row) * K + k0 + gc * 8]);
      ld16(&Bs[r0 * 32], &Bt[(size_t)(bn + row) * K + k0 + gc * 8]);
    }
    __syncthreads();
    short8 af[4], bf[4];
#pragma unroll
    for (int mi = 0; mi < 4; ++mi) {
      int m = wr * 64 + mi * 16 + l15;
      af[mi] = *(const short8*)&As[m * 32 + (quad ^ ((m >> 1) & 3)) * 8];
    }
#pragma unroll
    for (int ni = 0; ni < 4; ++ni) {
      int n = wc * 64 + ni * 16 + l15;
      bf[ni] = *(const short8*)&Bs[n * 32 + (quad ^ ((n >> 1) & 3)) * 8];
    }
#pragma unroll
    for (int mi = 0; mi < 4; ++mi)
#pragma unroll
      for (int ni = 0; ni < 4; ++ni)
        acc[mi][ni] = __builtin_amdgcn_mfma_f32_16x16x32_bf16(af[mi], bf[ni], acc[mi][ni], 0, 0, 0);
  }
  // epilogue: C/D layout col=lane&15, row=quad*4+reg
#pragma unroll
  for (int mi = 0; mi < 4; ++mi)
#pragma unroll
    for (int ni = 0; ni < 4; ++ni)
#pragma unroll
      for (int r = 0; r < 4; ++r) {
        int grow = bm + wr * 64 + mi * 16 + quad * 4 + r;
        int gcol = bn + wc * 64 + ni * 16 + l15;
        if constexpr (__is_same(OutT, ushort))
          C[(size_t)grow * N + gcol] = f2bf(acc[mi][ni][r]);
        else
          C[(size_t)grow * N + gcol] = acc[mi][ni][r];
      }
}

// ---------------------------------------------------------------------------
// gemm1 variant: identical main loop; epilogue writes V column-strips
// (bn >= 2560) TRANSPOSED directly into vT[512][4096] (replaces the separate
// transpose_v kernel: saves 4MB read + 4MB write + a launch). Lane packs
// acc[mi][ni][0..3] = 4 consecutive token-rows at fixed head-dim d into ONE
// 8B ushort4 store — better coalesced than the 4 scalar C stores it replaces.
// qkv's V columns are never written (attn reads V only via vT). Branch is
// block-uniform; no extra live state (spill-safe).
// ---------------------------------------------------------------------------
__global__ __launch_bounds__(256) void gemm_qkv(const ushort* __restrict__ A,
                                                const ushort* __restrict__ Bt,
                                                ushort* __restrict__ C,
                                                ushort* __restrict__ vT,
                                                int M, int N, int K) {
  __shared__ __align__(16) ushort As[128 * 32];
  __shared__ __align__(16) ushort Bs[128 * 32];
  const int tid = threadIdx.x;
  const int w = tid >> 6, l = tid & 63;
  const int wr = w >> 1, wc = w & 1;
  const int quad = l >> 4, l15 = l & 15;
  const int bm = blockIdx.y * 128, bn = blockIdx.x * 128;

  f32x4 acc[4][4];
#pragma unroll
  for (int mi = 0; mi < 4; ++mi)
#pragma unroll
    for (int ni = 0; ni < 4; ++ni)
#pragma unroll
      for (int r = 0; r < 4; ++r) acc[mi][ni][r] = 0.f;

  for (int k0 = 0; k0 < K; k0 += 32) {
    __syncthreads();
#pragma unroll
    for (int j = 0; j < 2; ++j) {
      int r0 = w * 32 + j * 16;
      int row = r0 + (l >> 2);
      int gc = (l & 3) ^ ((row >> 1) & 3);
      ld16(&As[r0 * 32], &A[(size_t)(bm + row) * K + k0 + gc * 8]);
      ld16(&Bs[r0 * 32], &Bt[(size_t)(bn + row) * K + k0 + gc * 8]);
    }
    __syncthreads();
    short8 af[4], bf[4];
#pragma unroll
    for (int mi = 0; mi < 4; ++mi) {
      int m = wr * 64 + mi * 16 + l15;
      af[mi] = *(const short8*)&As[m * 32 + (quad ^ ((m >> 1) & 3)) * 8];
    }
#pragma unroll
    for (int ni = 0; ni < 4; ++ni) {
      int n = wc * 64 + ni * 16 + l15;
      bf[ni] = *(const short8*)&Bs[n * 32 + (quad ^ ((n >> 1) & 3)) * 8];
    }
#pragma unroll
    for (int mi = 0; mi < 4; ++mi)
#pragma unroll
      for (int ni = 0; ni < 4; ++ni)
        acc[mi][ni] = __builtin_amdgcn_mfma_f32_16x16x32_bf16(af[mi], bf[ni], acc[mi][ni], 0, 0, 0);
  }

  if (bn >= 2560) {
    // V strip -> vT[d][m], d = gcol-2560, m = token row. 4 rows packed / store.
#pragma unroll
    for (int mi = 0; mi < 4; ++mi)
#pragma unroll
      for (int ni = 0; ni < 4; ++ni) {
        int d = bn - 2560 + wc * 64 + ni * 16 + l15;
        int m = bm + wr * 64 + mi * 16 + quad * 4;
        ushort4 o;
        o.x = f2bf(acc[mi][ni][0]); o.y = f2bf(acc[mi][ni][1]);
        o.z = f2bf(acc[mi][ni][2]); o.w = f2bf(acc[mi][ni][3]);
        *(ushort4*)&vT[(size_t)d * 4096 + m] = o;
      }
  } else {
#pragma unroll
    for (int mi = 0; mi < 4; ++mi)
#pragma unroll
      for (int ni = 0; ni < 4; ++ni)
#pragma unroll
        for (int r = 0; r < 4; ++r) {
          int grow = bm + wr * 64 + mi * 16 + quad * 4 + r;
          int gcol = bn + wc * 64 + ni * 16 + l15;
          C[(size_t)grow * N + gcol] = f2bf(acc[mi][ni][r]);
        }
  }
}

// ---------------------------------------------------------------------------
// RoPE in-place on bf16 K columns of qkv [4096][3072] (cols 2048..2559).
// Vectorized: 2 pairs (8B) per thread. Q rope is fused into attn.
// ---------------------------------------------------------------------------
__global__ __launch_bounds__(256) void rope_k_bf16(ushort* __restrict__ qkv) {
  int idx = blockIdx.x * 256 + threadIdx.x;  // 0..524287, exact
  int row = idx >> 7;
  int kp0 = (idx & 127) << 1;
  int t = row & (T_SEQ - 1);
  ushort* ptr = qkv + (size_t)row * 3072 + 2048 + 2 * kp0;
  ushort4 v = *(const ushort4*)ptr;
  int i0 = kp0 & 63, i1 = (kp0 + 1) & 63;
  float sn0, cs0, sn1, cs1;
  sincosf((float)t * expf((float)i0 * -0.14391156831212788f), &sn0, &cs0);
  sincosf((float)t * expf((float)i1 * -0.14391156831212788f), &sn1, &cs1);
  float a0 = bf2f(v.x), b0 = bf2f(v.y);
  float a1 = bf2f(v.z), b1 = bf2f(v.w);
  ushort4 o;
  o.x = f2bf(a0 * cs0 - b0 * sn0); o.y = f2bf(a0 * sn0 + b0 * cs0);
  o.z = f2bf(a1 * cs1 - b1 * sn1); o.w = f2bf(a1 * sn1 + b1 * cs1);
  *(ushort4*)ptr = o;
}

// ---------------------------------------------------------------------------
// MFMA flash attention v5 (round-0 exact — 77us measured; v6-v9 occupancy
// experiments all regressed: 80KB never fits 2/CU, and every LDS-footprint
// cut cost the pipeline more than 2-block TLP paid back. Keep.)
// grid (32, NKV, B), 512 thr = 8 waves. Block covers 4 q-heads x 32 q-rows
// sharing K/V staging; two complementary q-tiles (63-bx, bx) -> exactly 33
// k-iters/block, 256-block balanced grid. No-max softmax, double-buffered
// K/V, SC folded into Q frags, truncated P converts. LDS 80KB.
// ---------------------------------------------------------------------------
__global__ __launch_bounds__(512, 2) void attn_mfma(const ushort* __restrict__ qkv,
                                                    const ushort* __restrict__ vT,
                                                    ushort* __restrict__ ao) {
  __shared__ __align__(16) ushort Ks[2][64 * 128];
  __shared__ __align__(16) ushort Vt[2][128 * 64];
  __shared__ __align__(16) ushort Ps[8][16 * 64];
  const int tid = threadIdx.x;
  const int w = tid >> 6, l = tid & 63;
  const int quad = l >> 4, l15 = l & 15;
  const int hw = w >> 1, sub = w & 1;
  const int kvh = blockIdx.y, b = blockIdx.z;
  const int h = kvh * 4 + hw;
  const size_t krow0 = (size_t)b * T_SEQ;
  const float SC = 0.12751744595764253f;  // (1/sqrt(128)) * log2(e)

  ushort* pw = Ps[w];
  const int within = l & 7;
  const int colbase = l15 >> 3;  // 0 or 1

  auto stage = [&](int kt, int bufi) {
    const int kt0 = kt << 6;
    ushort* kb = Ks[bufi];
    ushort* vb = Vt[bufi];
#pragma unroll
    for (int j = 0; j < 2; ++j) {  // K tile 64x128
      int r0 = w * 8 + j * 4;
      int row = r0 + (l >> 4);
      int gc = (l & 15) ^ ((row >> 1) & 7);
      ld16(&kb[r0 * 128], &qkv[(krow0 + kt0 + row) * 3072 + 2048 + kvh * 128 + gc * 8]);
    }
#pragma unroll
    for (int j = 0; j < 2; ++j) {  // V^T tile 128x64
      int r0 = w * 16 + j * 8;
      int row = r0 + (l >> 3);
      int gc = (l & 7) ^ (row & 7);
      ld16(&vb[r0 * 64], &vT[(size_t)(kvh * 128 + row) * 4096 + krow0 + kt0 + gc * 8]);
    }
  };

#pragma unroll 1
  for (int ph = 0; ph < 2; ++ph) {
    const int qt = ph ? (int)blockIdx.x : 63 - (int)blockIdx.x;
    const int qt0 = qt << 5;
    const size_t qrow0 = krow0 + qt0;

    // Q fragments in registers; RoPE + SC folded in.
    const int t_pos = qt0 + sub * 16 + l15;
    short8 qf[4];
#pragma unroll
    for (int kc = 0; kc < 4; ++kc) {
      short8 raw = *(const short8*)&qkv[(qrow0 + sub * 16 + l15) * 3072 + h * 128 + kc * 32 + quad * 8];
#pragma unroll
      for (int u = 0; u < 4; ++u) {
        int i_idx = kc * 16 + quad * 4 + u;
        float inv = expf((float)i_idx * -0.14391156831212788f);  // ln(10000)/64
        float sn, cs;
        sincosf((float)t_pos * inv, &sn, &cs);
        cs *= SC; sn *= SC;
        float x1 = bf2f((ushort)raw[2 * u]);
        float x2 = bf2f((ushort)raw[2 * u + 1]);
        qf[kc][2 * u]     = (short)f2bf(x1 * cs - x2 * sn);
        qf[kc][2 * u + 1] = (short)f2bf(x1 * sn + x2 * cs);
      }
    }

    f32x4 oacc[8];
#pragma unroll
    for (int i = 0; i < 8; ++i)
#pragma unroll
      for (int r = 0; r < 4; ++r) oacc[i][r] = 0.f;
    float lpart[4] = {0.f, 0.f, 0.f, 0.f};

    const int nkt = (qt >> 1) + 1;
    __syncthreads();  // prior phase's LDS reads complete before re-priming
    stage(0, 0);
    for (int kt = 0; kt < nkt; ++kt) {
      __syncthreads();  // (vmcnt drain) stage(kt) landed; prior buffer free
      if (kt + 1 < nkt) stage(kt + 1, (kt + 1) & 1);
      const ushort* kb = Ks[kt & 1];
      const ushort* vb = Vt[kt & 1];

      // S = Q K^T (wave rows sub*16.., cols 0..63); already scaled by SC
      f32x4 sacc[4];
#pragma unroll
      for (int ni = 0; ni < 4; ++ni)
#pragma unroll
        for (int r = 0; r < 4; ++r) sacc[ni][r] = 0.f;
#pragma unroll
      for (int kc = 0; kc < 4; ++kc) {
#pragma unroll
        for (int ni = 0; ni < 4; ++ni) {
          int n = ni * 16 + l15;
          short8 bfr = *(const short8*)&kb[n * 128 + ((kc * 4 + quad) ^ ((n >> 1) & 7)) * 8];
          sacc[ni] = __builtin_amdgcn_mfma_f32_16x16x32_bf16(qf[kc], bfr, sacc[ni], 0, 0, 0);
        }
      }

      // p = exp2(s); stream to LDS (truncated bf16); accumulate partial l.
      const int kt0 = kt << 6;
      if (kt == nkt - 1) {  // diagonal tile: causal mask
        const int rowg = qt0 + sub * 16 + quad * 4;
#pragma unroll
        for (int ni = 0; ni < 4; ++ni) {
          const int colid = kt0 + ni * 16 + l15;
#pragma unroll
          for (int r = 0; r < 4; ++r) {
            float s = (colid > rowg + r) ? -1e30f : sacc[ni][r];
            float pv = __builtin_amdgcn_exp2f(s);
            lpart[r] += pv;
            int prow = quad * 4 + r;
            pw[prow * 64 + (((ni * 2 + colbase) ^ (prow & 7)) << 3) + within] = f2bf_trunc(pv);
          }
        }
      } else {
#pragma unroll
        for (int ni = 0; ni < 4; ++ni)
#pragma unroll
          for (int r = 0; r < 4; ++r) {
            float pv = __builtin_amdgcn_exp2f(sacc[ni][r]);
            lpart[r] += pv;
            int prow = quad * 4 + r;
            pw[prow * 64 + (((ni * 2 + colbase) ^ (prow & 7)) << 3) + within] = f2bf_trunc(pv);
          }
      }

      // O += P V  (A = Ps rows m=l&15, B = Vt rows d)
#pragma unroll
      for (int kc = 0; kc < 2; ++kc) {
        short8 a = *(const short8*)&pw[l15 * 64 + ((kc * 4 + quad) ^ (l15 & 7)) * 8];
#pragma unroll
        for (int ni2 = 0; ni2 < 8; ++ni2) {
          int d = ni2 * 16 + l15;
          short8 bfr = *(const short8*)&vb[d * 64 + ((kc * 4 + quad) ^ (d & 7)) * 8];
          oacc[ni2] = __builtin_amdgcn_mfma_f32_16x16x32_bf16(a, bfr, oacc[ni2], 0, 0, 0);
        }
      }
    }

    // phase epilogue: one butterfly reduce of l per row, normalize + store
#pragma unroll
    for (int r = 0; r < 4; ++r) {
      float lv = lpart[r];
      lv += __shfl_xor(lv, 1);
      lv += __shfl_xor(lv, 2);
      lv += __shfl_xor(lv, 4);
      lv += __shfl_xor(lv, 8);
      float inv = 1.f / lv;
      size_t grow = qrow0 + sub * 16 + quad * 4 + r;
#pragma unroll
      for (int ni2 = 0; ni2 < 8; ++ni2)
        ao[grow * 2048 + h * 128 + ni2 * 16 + l15] = f2bf(oacc[ni2][r] * inv);
    }
  }
}

// ---------------------------------------------------------------------------
extern "C" void kernel_launch(void* const* d_in, const int* in_sizes, int n_in,
                              void* d_out, int out_size, void* d_ws, size_t ws_size,
                              hipStream_t stream) {
  const float* x  = (const float*)d_in[0];
  const float* Wq = (const float*)d_in[1];
  const float* Wk = (const float*)d_in[2];
  const float* Wv = (const float*)d_in[3];
  const float* Wo = (const float*)d_in[4];
  float* y = (float*)d_out;

  const int M = BATCH * T_SEQ;  // 4096
  ushort* xb    = (ushort*)d_ws;                    // 4096*2048  (16 MB)
  ushort* wqkvT = xb + (size_t)M * 2048;            // 3072*2048  (12 MB)
  ushort* woT   = wqkvT + (size_t)3072 * 2048;      // 2048*2048  ( 8 MB)
  ushort* qkv   = woT + (size_t)2048 * 2048;        // 4096*3072  (24 MB)
  ushort* vTb   = qkv + (size_t)M * 3072;           // 512*4096   ( 4 MB)
  ushort* aob   = vTb + (size_t)512 * 4096;         // 4096*2048  (16 MB)

  prep<<<18432, 256, 0, stream>>>(x, xb, Wq, Wk, Wv, Wo, wqkvT, woT);

  // gemm1 with fused V-transpose epilogue (writes qkv Q/K cols + vT directly)
  gemm_qkv<<<dim3(3072 / 128, M / 128), 256, 0, stream>>>(
      xb, wqkvT, qkv, vTb, M, 3072, 2048);

  rope_k_bf16<<<2048, 256, 0, stream>>>(qkv);

  attn_mfma<<<dim3(32, NKV, BATCH), 512, 0, stream>>>(qkv, vTb, aob);

  gemm_bt<float><<<dim3(2048 / 128, M / 128), 256, 0, stream>>>(
      aob, woT, y, M, 2048, 2048);
}